// Round 18
// baseline (1486.710 us; speedup 1.0000x reference)
//
#include <hip/hip_runtime.h>

typedef __bf16 bf16;
typedef bf16 bf16x8 __attribute__((ext_vector_type(8)));
typedef bf16 bf16x4 __attribute__((ext_vector_type(4)));
typedef float f32x4 __attribute__((ext_vector_type(4)));

#define NB 256
#define TS 64
#define DD 1024
#define HH 1024
#define NOUT 4096

// Column permutation (all weight/preact tensors): cx = (h>>4)*64 + (h&15)*4 + g
// (original col co = g*1024 + h). wg "ht" owns cx in [ht*64,+64) = 16 h x 4
// gates; cell thread (n,hl) reads its 4 gates as ONE bf16x4.
// Fragment tiles: 16col x 32k of 512 bf16; element (l,j): col=base+(l&15),
// k=kbase+(l>>4)*8+j (mfma_16x16x32 operand layout; linear LDS staging).
// Layouts: x_bf [t][n][d]; xWx2 [t][n][cx] bf16 +bias; G2 [n][cx][p].
// Step kernel reads A-operand fragments DIRECTLY global->reg (Aop is 512 KB,
// L2-resident -- LDS staging was pure overhead per common-mistake #7/m169).

static __device__ __forceinline__ void gload_lds16(const void* g, void* l) {
  __builtin_amdgcn_global_load_lds(
      (const __attribute__((address_space(1))) void*)g,
      (__attribute__((address_space(3))) void*)l, 16, 0, 0);
}

#define SWZ_ADD(v, imm) \
  (v) += __int_as_float(__builtin_amdgcn_ds_swizzle(__float_as_int(v), imm))
#define SWZ_MAX(v, imm) \
  (v) = fmaxf(v, __int_as_float(__builtin_amdgcn_ds_swizzle(__float_as_int(v), imm)))

// ---- one-time converts ------------------------------------------------------
// x (f32 [n][t][d]) -> x_bf (bf16 [t][n][d]).
__global__ __launch_bounds__(256) void convert_x(const float* __restrict__ x,
                                                 bf16* __restrict__ xb) {
  const int gid = blockIdx.x * 256 + threadIdx.x;
  const int t = gid >> 15;
  const int rem = gid & 32767;
  const int n = rem >> 7;
  const int d = (rem & 127) * 8;
  const float* src = x + ((size_t)n * TS + t) * DD + d;
  bf16x8 v;
#pragma unroll
  for (int j = 0; j < 8; ++j) v[j] = (bf16)src[j];
  *(bf16x8*)(xb + (size_t)gid * 8) = v;
}

// One pass over A: emits A_bf, At, h0/c0, Aop0, step-0 scores s0.
__global__ __launch_bounds__(1024) void prep_A(const float* __restrict__ A,
                                               bf16* __restrict__ A_bf,
                                               bf16* __restrict__ At,
                                               float* __restrict__ c_ws,
                                               bf16* __restrict__ Aop0,
                                               float* __restrict__ s0) {
  __shared__ float lt[1024 * 17];
  __shared__ float h_sh[1024];
  __shared__ float scA[16], scB[16];
  const int n = (blockIdx.x & 7) * 32 + (blockIdx.x >> 3);
  const int u = threadIdx.x;
  const float* ar = A + ((size_t)n * HH + u) * 16;
  float a[16];
#pragma unroll
  for (int q = 0; q < 4; ++q) {
    const f32x4 v = *(const f32x4*)(ar + q * 4);
#pragma unroll
    for (int r = 0; r < 4; ++r) {
      a[q * 4 + r] = v[r];
      lt[u * 17 + q * 4 + r] = v[r];
    }
  }
  {
    bf16x8 b0, b1;
#pragma unroll
    for (int j = 0; j < 8; ++j) { b0[j] = (bf16)a[j]; b1[j] = (bf16)a[8 + j]; }
    bf16* abf = A_bf + ((size_t)n * HH + u) * 16;
    *(bf16x8*)abf = b0;
    *(bf16x8*)(abf + 8) = b1;
  }
  float h0 = 0.f;
#pragma unroll
  for (int p = 0; p < 16; ++p) h0 += a[p];
  h0 *= 0.0625f;
  c_ws[(n << 10) + u] = h0;
  h_sh[u] = h0;
  Aop0[(n << 10) + u] = (bf16)h0;
  __syncthreads();
  {
    const int p = u >> 6, seg = u & 63;
    bf16x8 o0, o1;
#pragma unroll
    for (int j = 0; j < 8; ++j) {
      o0[j] = (bf16)lt[(seg * 16 + j) * 17 + p];
      o1[j] = (bf16)lt[(seg * 16 + 8 + j) * 17 + p];
    }
    bf16* dst = At + (size_t)(n * 16 + p) * 1024 + seg * 16;
    *(bf16x8*)dst = o0;
    *(bf16x8*)(dst + 8) = o1;
  }
  {
    const int lane = u & 63, w = u >> 6;
    float s = 0.f;
#pragma unroll
    for (int i = 0; i < 16; ++i) {
      const int idx = lane + 64 * i;
      s = fmaf(h_sh[idx], lt[idx * 17 + w], s);
    }
    SWZ_ADD(s, 0x041F); SWZ_ADD(s, 0x081F); SWZ_ADD(s, 0x101F);
    SWZ_ADD(s, 0x201F); SWZ_ADD(s, 0x401F);
    if (lane == 0) scA[w] = s;
    else if (lane == 32) scB[w] = s;
  }
  __syncthreads();
  if (u < 16) s0[n * 16 + u] = scA[u] + scB[u];
}

// W (1024 x 4096 f32) -> cx-permuted fragment tiles, coalesced reads.
__global__ __launch_bounds__(256) void convert_wt2(const float* __restrict__ W,
                                                   bf16* __restrict__ Wt) {
  __shared__ bf16 lb[8 * 4096];  // 64 KB: [row j][cx]
  const int kb = blockIdx.x;
  const int kt = kb >> 2, group = kb & 3;
  const int tid = threadIdx.x;
#pragma unroll
  for (int qq = 0; qq < 32; ++qq) {
    const int chunk = qq * 256 + tid;
    const int row = chunk >> 10;
    const int colb = (chunk & 1023) * 4;
    const f32x4 v = *(const f32x4*)(W + (size_t)(kb * 8 + row) * NOUT + colb);
#pragma unroll
    for (int e = 0; e < 4; ++e) {
      const int co = colb + e;
      const int hh = co & 1023, g = co >> 10;
      const int cx = (hh >> 4) * 64 + (hh & 15) * 4 + g;
      lb[row * 4096 + cx] = (bf16)v[e];
    }
  }
  __syncthreads();
  const int tau = tid;  // all 256 taus
  bf16* wbase = Wt + (size_t)(tau * 32 + kt) * 512 + group * 16 * 8;
#pragma unroll
  for (int c = 0; c < 16; ++c) {
    const int cx = tau * 16 + c;
    bf16x8 o;
#pragma unroll
    for (int j = 0; j < 8; ++j) o[j] = lb[j * 4096 + cx];
    *(bf16x8*)(wbase + c * 8) = o;
  }
}

// ---- 128x128 / BK=32 GEMM (m97 structure), bf16 out, ct-pinned swizzle ------
// MODE 0 (4096 wgs, rows = t*NB+n): plain row-major [t][n][col], bias folded.
// MODE 1 (1024 wgs, rows = n*16+p): write [n][col][p].
// (R17 lesson: NO nt stores here -- 2-byte nt defeats write-combining, +22 us.)
template <int MODE>
__global__ __launch_bounds__(256, 4) void gemm128(const bf16* __restrict__ Am,
                                                  const bf16* __restrict__ Bt,
                                                  bf16* __restrict__ C,
                                                  const float* __restrict__ bias) {
  __shared__ __align__(16) bf16 astg[2][8 * 512];
  __shared__ __align__(16) bf16 bstg[2][8 * 512];
  const int b = blockIdx.x;
  const int ct = (b & 7) * 4 + ((b >> 3) & 3);
  const int rt = b >> 5;
  const int tid = threadIdx.x, lane = tid & 63, wid = tid >> 6;
  const int wr = wid >> 1, wc = wid & 1;

  const bf16* gA[2];
  const bf16* gB[2];
  int lA[2], lB[2];
#pragma unroll
  for (int e = 0; e < 2; ++e) {
    const int mt = wid * 2 + e;
    gA[e] = Am + (size_t)(rt * 128 + mt * 16 + (lane & 15)) * 1024 + (lane >> 4) * 8;
    lA[e] = mt * 512;
    gB[e] = Bt + ((size_t)(ct * 8 + mt) * 32) * 512 + lane * 8;
    lB[e] = mt * 512;
  }
  f32x4 acc[4][4];
#pragma unroll
  for (int i = 0; i < 4; ++i)
#pragma unroll
    for (int j = 0; j < 4; ++j) acc[i][j] = (f32x4){0, 0, 0, 0};

#pragma unroll
  for (int e = 0; e < 2; ++e) {
    gload_lds16(gA[e], &astg[0][lA[e]]);
    gload_lds16(gB[e], &bstg[0][lB[e]]);
  }
  for (int it = 0; it < 32; ++it) {
    __syncthreads();
    if (it < 31) {
#pragma unroll
      for (int e = 0; e < 2; ++e) {
        gload_lds16(gA[e] + (it + 1) * 32, &astg[(it + 1) & 1][lA[e]]);
        gload_lds16(gB[e] + (size_t)(it + 1) * 512, &bstg[(it + 1) & 1][lB[e]]);
      }
    }
    const bf16* ab = astg[it & 1];
    const bf16* bb = bstg[it & 1];
    bf16x8 af[4], bfr[4];
#pragma unroll
    for (int i = 0; i < 4; ++i) af[i] = *(const bf16x8*)(ab + (wr * 4 + i) * 512 + lane * 8);
#pragma unroll
    for (int j = 0; j < 4; ++j) bfr[j] = *(const bf16x8*)(bb + (wc * 4 + j) * 512 + lane * 8);
#pragma unroll
    for (int i = 0; i < 4; ++i)
#pragma unroll
      for (int j = 0; j < 4; ++j)
        acc[i][j] = __builtin_amdgcn_mfma_f32_16x16x32_bf16(af[i], bfr[j], acc[i][j], 0, 0, 0);
  }
  // C/D layout: col=lane&15, row=(lane>>4)*4+r [m89-verified]
#pragma unroll
  for (int j = 0; j < 4; ++j) {
    const int col = ct * 128 + wc * 64 + j * 16 + (lane & 15);
    float bv = 0.f;
    if (MODE == 0) {
      const int rem = col & 63;
      bv = bias[(rem & 3) * HH + (col >> 6) * 16 + (rem >> 2)];
    }
#pragma unroll
    for (int i = 0; i < 4; ++i) {
      const int row0 = rt * 128 + wr * 64 + i * 16 + (lane >> 4) * 4;
#pragma unroll
      for (int r = 0; r < 4; ++r) {
        const int row = row0 + r;
        size_t idx;
        if (MODE == 0) idx = (size_t)row * NOUT + col;  // rows are t*NB+n
        else           idx = (size_t)(row >> 4) * (NOUT * 16) + (size_t)col * 16 + (row & 15);
        C[idx] = (bf16)(acc[i][j][r] + bv);
      }
    }
  }
}

// ---- per-step kernel: NO LDS staging (A-frags direct global->reg from the
//      L2-resident 512 KB Aop). One barrier before cell instead of three. ----
#define STEP_SMEM 36864  // red union only (36 KB)
__global__ __launch_bounds__(512, 4) void step_kernel(
    const bf16* __restrict__ Aop_cur, bf16* __restrict__ Aop_nxt,
    const bf16* __restrict__ Wh_t, const bf16* __restrict__ xWx2,
    const bf16* __restrict__ G2, const float* __restrict__ s_cur,
    float* __restrict__ s_nxt, float* __restrict__ s_zro,
    const bf16* __restrict__ A_bf, float* __restrict__ c_ws,
    float* __restrict__ out, const int t) {
  __shared__ __align__(16) float red[9216];  // [kg*64+c][36] / tail transpose
  __shared__ float w_sh[512];

  const int b = blockIdx.x;
  const int xcd = b & 7;
  const int ht = xcd * 8 + ((b >> 3) & 7);  // [0,64)
  const int rt = b >> 6;                    // [0,8)
  const int tid = threadIdx.x, lane = tid & 63, wid = tid >> 6;
  const int kg = wid >> 1, ow = wid & 1;
  const int nloc = tid >> 4, hl = tid & 15;
  const int n = rt * 32 + nloc, h = ht * 16 + hl;

  // score read FIRST
  float ss = s_cur[n * 16 + hl];

  // A-fragments direct global->reg: wave (kg,ow) needs rows rt*32..+32,
  // K slice kg*256..+256. Same per-lane gather the LDS staging used.
  const bf16* aBase0 = Aop_cur + (size_t)(rt * 32 + (lane & 15)) * 1024 +
                       kg * 256 + (lane >> 4) * 8;
  const bf16* aBase1 = aBase0 + 16 * 1024;
  bf16x8 af0[8], af1[8];
#pragma unroll
  for (int ks = 0; ks < 8; ++ks) {
    af0[ks] = *(const bf16x8*)(aBase0 + ks * 32);
    af1[ks] = *(const bf16x8*)(aBase1 + ks * 32);
  }

  // other independent early loads
  const bf16x4 xv = *(const bf16x4*)(xWx2 + (size_t)t * (NB * NOUT) +
                                     (size_t)n * NOUT + ht * 64 + hl * 4);
  const float cold = c_ws[(n << 10) + h];
  const bf16* gB0 = Wh_t + ((size_t)(ht * 4 + ow * 2 + 0) * 32 + kg * 8) * 512 + lane * 8;
  const bf16* gB1 = Wh_t + ((size_t)(ht * 4 + ow * 2 + 1) * 32 + kg * 8) * 512 + lane * 8;
  bf16x8 bc0 = *(const bf16x8*)gB0;
  bf16x8 bc1 = *(const bf16x8*)gB1;
  if (tid < 8) s_zro[b * 8 + tid] = 0.f;  // zero t+2 score buffer

  // softmax over p within 16-lane groups (hides A-frag latency)
  {
    ss *= 0.03125f;  // 1/sqrt(1024)
    float m = ss;
    SWZ_MAX(m, 0x041F); SWZ_MAX(m, 0x081F); SWZ_MAX(m, 0x101F); SWZ_MAX(m, 0x201F);
    const float e = expf(ss - m);
    float su = e;
    SWZ_ADD(su, 0x041F); SWZ_ADD(su, 0x081F); SWZ_ADD(su, 0x101F); SWZ_ADD(su, 0x201F);
    w_sh[tid] = e / su;
  }

  // ---- GEMM: 8 ks x 4 MFMA from registers, B rolling 1-ahead. No barrier
  // needed first: no LDS dependency (compiler waits on the A/B loads). ----
  f32x4 a00 = {0, 0, 0, 0}, a01 = {0, 0, 0, 0}, a10 = {0, 0, 0, 0}, a11 = {0, 0, 0, 0};
  {
    __builtin_amdgcn_s_setprio(1);
#pragma unroll
    for (int ks = 0; ks < 8; ++ks) {
      bf16x8 bn0, bn1;
      if (ks < 7) {
        bn0 = *(const bf16x8*)(gB0 + (ks + 1) * 512);
        bn1 = *(const bf16x8*)(gB1 + (ks + 1) * 512);
      }
      a00 = __builtin_amdgcn_mfma_f32_16x16x32_bf16(af0[ks], bc0, a00, 0, 0, 0);
      a01 = __builtin_amdgcn_mfma_f32_16x16x32_bf16(af0[ks], bc1, a01, 0, 0, 0);
      a10 = __builtin_amdgcn_mfma_f32_16x16x32_bf16(af1[ks], bc0, a10, 0, 0, 0);
      a11 = __builtin_amdgcn_mfma_f32_16x16x32_bf16(af1[ks], bc1, a11, 0, 0, 0);
      if (ks < 7) { bc0 = bn0; bc1 = bn1; }
    }
    __builtin_amdgcn_s_setprio(0);
  }

  // G2 block issued now (A-frag regs freed); latency hides under red+barrier
  bf16x8 gq[8];
  {
    const bf16* Gp = G2 + (size_t)n * (NOUT * 16) + (size_t)(ht * 64 + hl * 4) * 16;
#pragma unroll
    for (int e = 0; e < 8; ++e) gq[e] = *(const bf16x8*)(Gp + e * 8);
  }

  // fragment -> red[(kg*64 + c)*36 + nn]; c = ow*32 + j*16 + (lane&15)
  {
    const int cb = kg * 64 + ow * 32 + (lane & 15);
    const int nb = (lane >> 4) * 4;
    *(f32x4*)&red[(cb)*36 + nb] = a00;
    *(f32x4*)&red[(cb + 16) * 36 + nb] = a01;
    *(f32x4*)&red[(cb)*36 + nb + 16] = a10;
    *(f32x4*)&red[(cb + 16) * 36 + nb + 16] = a11;
  }
  __syncthreads();  // red + w_sh writes visible -> cell

  // ---- cell ----
  f32x4 gv = {0, 0, 0, 0};
#pragma unroll
  for (int k2 = 0; k2 < 4; ++k2)
#pragma unroll
    for (int g = 0; g < 4; ++g) gv[g] += red[(k2 * 64 + hl * 4 + g) * 36 + nloc];
#pragma unroll
  for (int g = 0; g < 4; ++g) {
    float a0 = 0.f;
#pragma unroll
    for (int p = 0; p < 8; ++p) a0 = fmaf(w_sh[nloc * 16 + p], (float)gq[g * 2][p], a0);
#pragma unroll
    for (int p = 0; p < 8; ++p) a0 = fmaf(w_sh[nloc * 16 + 8 + p], (float)gq[g * 2 + 1][p], a0);
    gv[g] += a0;
  }
  const float ai = gv[0] + (float)xv[0];
  const float af = gv[1] + (float)xv[1];
  const float ao = gv[2] + (float)xv[2];
  const float ag = gv[3] + (float)xv[3];
  const float si = 1.f / (1.f + expf(-ai));
  const float sf = 1.f / (1.f + expf(-af));
  const float so = 1.f / (1.f + expf(-ao));
  const float cn = sf * cold + si * tanhf(ag);
  const float hn = so * tanhf(cn);
  c_ws[(n << 10) + h] = cn;
  __builtin_nontemporal_store(hn, &out[((size_t)n * TS + t) * HH + h]);
  Aop_nxt[(n << 10) + h] = (bf16)hn;

  if (t < TS - 1) {  // next-step score partials: LDS transpose + atomicAdd
    __syncthreads();  // red gate-reads done -> reuse as transpose buffer
    const bf16* arow = A_bf + ((size_t)n * HH + h) * 16;
    const bf16x8 av0 = *(const bf16x8*)arow;
    const bf16x8 av1 = *(const bf16x8*)(arow + 8);
#pragma unroll
    for (int r = 0; r < 8; ++r) {
      red[(nloc * 16 + r) * 17 + hl] = hn * (float)av0[r];
      red[(nloc * 16 + 8 + r) * 17 + hl] = hn * (float)av1[r];
    }
    __syncthreads();
    const float* r2 = &red[(nloc * 16 + hl) * 17];  // p = hl, sum over 16 h
    float s = 0.f;
#pragma unroll
    for (int q = 0; q < 16; ++q) s += r2[q];
    atomicAdd(&s_nxt[n * 16 + hl], s);  // device-scope [m20]
  }
}

// ---------------------------------------------------------------------------
// ws layout (bytes), ~245 MB of 256 MiB:
//   [0, 8388608)             Wh_t   bf16 tiles (1024x4096, cx cols)
//   [8388608, 16777216)      Wat_t  bf16 tiles (1024x4096, cx cols)
//   [16777216, 25165824)     At     bf16 (4096x1024)
//   [25165824, 33554432)     A_bf   bf16 (256x1024x16)
//   [33554432, 167772160)    xWx2   bf16 [t][n][cx] (+bias)
//   [167772160, 201326592)   G2     bf16 [n][cx][p]
//   [201326592, 234881024)   x_bf   bf16 [t][n][d]   [transient]
//   [234881024, 243269632)   Wxt    bf16 tiles        [transient]
//   [243269632, 243793920)   Aop0   bf16 (256x1024)
//   [243793920, 244318208)   Aop1   bf16 (256x1024)
//   [244318208, 244334592)   s0     f32 (256x16)
//   [244334592, 244350976)   s1     f32 (256x16)  [memset 0 each call]
//   [244350976, 244367360)   s2     f32 (256x16)  [zeroed by step t=0]
//   [244367360, 245415936)   c_ws   f32 (256x1024)
// ---------------------------------------------------------------------------
extern "C" void kernel_launch(void* const* d_in, const int* in_sizes, int n_in,
                              void* d_out, int out_size, void* d_ws, size_t ws_size,
                              hipStream_t stream) {
  const float* x     = (const float*)d_in[0];
  const float* A     = (const float*)d_in[1];
  const float* Wx    = (const float*)d_in[2];
  const float* Wh    = (const float*)d_in[3];
  const float* Wattn = (const float*)d_in[4];
  const float* bias  = (const float*)d_in[5];
  float* out = (float*)d_out;
  char* ws = (char*)d_ws;
  bf16* Wh_t   = (bf16*)(ws + 0);
  bf16* Wat_t  = (bf16*)(ws + 8388608);
  bf16* At     = (bf16*)(ws + 16777216);
  bf16* A_bf   = (bf16*)(ws + 25165824);
  bf16* xWx2   = (bf16*)(ws + 33554432);
  bf16* G2     = (bf16*)(ws + 167772160);
  bf16* x_bf   = (bf16*)(ws + 201326592);
  bf16* Wxt    = (bf16*)(ws + 234881024);
  bf16* Aop0   = (bf16*)(ws + 243269632);
  bf16* Aop1   = (bf16*)(ws + 243793920);
  float* s0    = (float*)(ws + 244318208);
  float* s1    = (float*)(ws + 244334592);
  float* s2    = (float*)(ws + 244350976);
  float* c_ws  = (float*)(ws + 244367360);

  hipMemsetAsync(s1, 0, 16384, stream);
  convert_x<<<8192, 256, 0, stream>>>(x, x_bf);
  prep_A<<<256, 1024, 0, stream>>>(A, A_bf, At, c_ws, Aop0, s0);
  convert_wt2<<<128, 256, 0, stream>>>(Wx, Wxt);
  convert_wt2<<<128, 256, 0, stream>>>(Wh, Wh_t);
  convert_wt2<<<128, 256, 0, stream>>>(Wattn, Wat_t);
  gemm128<0><<<4096, 256, 0, stream>>>(x_bf, Wxt, xWx2, bias);  // x@Wx + bias
  gemm128<1><<<1024, 256, 0, stream>>>(At, Wat_t, G2, nullptr); // G2 = A^T@Wattn
  for (int t = 0; t < TS; ++t) {
    float* scur = (t % 3 == 0) ? s0 : (t % 3 == 1) ? s1 : s2;
    float* snxt = (t % 3 == 0) ? s1 : (t % 3 == 1) ? s2 : s0;
    float* szro = (t % 3 == 0) ? s2 : (t % 3 == 1) ? s0 : s1;
    step_kernel<<<512, 512, 0, stream>>>((t & 1) ? Aop1 : Aop0,
                                         (t & 1) ? Aop0 : Aop1, Wh_t, xWx2,
                                         G2, scur, snxt, szro, A_bf, c_ws,
                                         out, t);
  }
}

// Round 19
// 1354.898 us; speedup vs baseline: 1.0973x; 1.0973x over previous
//
#include <hip/hip_runtime.h>

typedef __bf16 bf16;
typedef bf16 bf16x8 __attribute__((ext_vector_type(8)));
typedef bf16 bf16x4 __attribute__((ext_vector_type(4)));
typedef float f32x4 __attribute__((ext_vector_type(4)));

#define NB 256
#define TS 64
#define DD 1024
#define HH 1024
#define NOUT 4096

// Column permutation (all weight/preact tensors): cx = (h>>4)*64 + (h&15)*4 + g
// (original col co = g*1024 + h). wg "ht" owns cx in [ht*64,+64) = 16 h x 4
// gates; cell thread (n,hl) reads its 4 gates as ONE bf16x4.
// Fragment tiles: 16col x 32k of 512 bf16; element (l,j): col=base+(l&15),
// k=kbase+(l>>4)*8+j (mfma_16x16x32 operand layout; linear LDS staging).
// Layouts: x_bf [t][n][d]; xWx2 [t][n][cx] bf16 +bias; G2 [n][cx][p].
// Step kernel: LDS staging via global_load_lds (R18 lesson: direct
// global->reg A-frags cost +1.9us/step -- DMA staging is free when its
// latency is hidden by early-issued independent loads).

static __device__ __forceinline__ void gload_lds16(const void* g, void* l) {
  __builtin_amdgcn_global_load_lds(
      (const __attribute__((address_space(1))) void*)g,
      (__attribute__((address_space(3))) void*)l, 16, 0, 0);
}

#define SWZ_ADD(v, imm) \
  (v) += __int_as_float(__builtin_amdgcn_ds_swizzle(__float_as_int(v), imm))
#define SWZ_MAX(v, imm) \
  (v) = fmaxf(v, __int_as_float(__builtin_amdgcn_ds_swizzle(__float_as_int(v), imm)))

// ---- one-time converts ------------------------------------------------------
// x (f32 [n][t][d]) -> x_bf (bf16 [t][n][d]).
__global__ __launch_bounds__(256) void convert_x(const float* __restrict__ x,
                                                 bf16* __restrict__ xb) {
  const int gid = blockIdx.x * 256 + threadIdx.x;
  const int t = gid >> 15;
  const int rem = gid & 32767;
  const int n = rem >> 7;
  const int d = (rem & 127) * 8;
  const float* src = x + ((size_t)n * TS + t) * DD + d;
  bf16x8 v;
#pragma unroll
  for (int j = 0; j < 8; ++j) v[j] = (bf16)src[j];
  *(bf16x8*)(xb + (size_t)gid * 8) = v;
}

// One pass over A: emits A_bf, At, h0/c0, Aop0, step-0 scores s0.
__global__ __launch_bounds__(1024) void prep_A(const float* __restrict__ A,
                                               bf16* __restrict__ A_bf,
                                               bf16* __restrict__ At,
                                               float* __restrict__ c_ws,
                                               bf16* __restrict__ Aop0,
                                               float* __restrict__ s0) {
  __shared__ float lt[1024 * 17];
  __shared__ float h_sh[1024];
  __shared__ float scA[16], scB[16];
  const int n = (blockIdx.x & 7) * 32 + (blockIdx.x >> 3);
  const int u = threadIdx.x;
  const float* ar = A + ((size_t)n * HH + u) * 16;
  float a[16];
#pragma unroll
  for (int q = 0; q < 4; ++q) {
    const f32x4 v = *(const f32x4*)(ar + q * 4);
#pragma unroll
    for (int r = 0; r < 4; ++r) {
      a[q * 4 + r] = v[r];
      lt[u * 17 + q * 4 + r] = v[r];
    }
  }
  {
    bf16x8 b0, b1;
#pragma unroll
    for (int j = 0; j < 8; ++j) { b0[j] = (bf16)a[j]; b1[j] = (bf16)a[8 + j]; }
    bf16* abf = A_bf + ((size_t)n * HH + u) * 16;
    *(bf16x8*)abf = b0;
    *(bf16x8*)(abf + 8) = b1;
  }
  float h0 = 0.f;
#pragma unroll
  for (int p = 0; p < 16; ++p) h0 += a[p];
  h0 *= 0.0625f;
  c_ws[(n << 10) + u] = h0;
  h_sh[u] = h0;
  Aop0[(n << 10) + u] = (bf16)h0;
  __syncthreads();
  {
    const int p = u >> 6, seg = u & 63;
    bf16x8 o0, o1;
#pragma unroll
    for (int j = 0; j < 8; ++j) {
      o0[j] = (bf16)lt[(seg * 16 + j) * 17 + p];
      o1[j] = (bf16)lt[(seg * 16 + 8 + j) * 17 + p];
    }
    bf16* dst = At + (size_t)(n * 16 + p) * 1024 + seg * 16;
    *(bf16x8*)dst = o0;
    *(bf16x8*)(dst + 8) = o1;
  }
  {
    const int lane = u & 63, w = u >> 6;
    float s = 0.f;
#pragma unroll
    for (int i = 0; i < 16; ++i) {
      const int idx = lane + 64 * i;
      s = fmaf(h_sh[idx], lt[idx * 17 + w], s);
    }
    SWZ_ADD(s, 0x041F); SWZ_ADD(s, 0x081F); SWZ_ADD(s, 0x101F);
    SWZ_ADD(s, 0x201F); SWZ_ADD(s, 0x401F);
    if (lane == 0) scA[w] = s;
    else if (lane == 32) scB[w] = s;
  }
  __syncthreads();
  if (u < 16) s0[n * 16 + u] = scA[u] + scB[u];
}

// W (1024 x 4096 f32) -> cx-permuted fragment tiles, coalesced reads.
__global__ __launch_bounds__(256) void convert_wt2(const float* __restrict__ W,
                                                   bf16* __restrict__ Wt) {
  __shared__ bf16 lb[8 * 4096];  // 64 KB: [row j][cx]
  const int kb = blockIdx.x;
  const int kt = kb >> 2, group = kb & 3;
  const int tid = threadIdx.x;
#pragma unroll
  for (int qq = 0; qq < 32; ++qq) {
    const int chunk = qq * 256 + tid;
    const int row = chunk >> 10;
    const int colb = (chunk & 1023) * 4;
    const f32x4 v = *(const f32x4*)(W + (size_t)(kb * 8 + row) * NOUT + colb);
#pragma unroll
    for (int e = 0; e < 4; ++e) {
      const int co = colb + e;
      const int hh = co & 1023, g = co >> 10;
      const int cx = (hh >> 4) * 64 + (hh & 15) * 4 + g;
      lb[row * 4096 + cx] = (bf16)v[e];
    }
  }
  __syncthreads();
  const int tau = tid;  // all 256 taus
  bf16* wbase = Wt + (size_t)(tau * 32 + kt) * 512 + group * 16 * 8;
#pragma unroll
  for (int c = 0; c < 16; ++c) {
    const int cx = tau * 16 + c;
    bf16x8 o;
#pragma unroll
    for (int j = 0; j < 8; ++j) o[j] = lb[j * 4096 + cx];
    *(bf16x8*)(wbase + c * 8) = o;
  }
}

// ---- 128x128 / BK=32 GEMM (m97 structure), bf16 out, ct-pinned swizzle ------
// MODE 0 (4096 wgs, rows = t*NB+n): plain row-major [t][n][col], bias folded.
// MODE 1 (1024 wgs, rows = n*16+p): write [n][col][p].
// Plain cached stores (R17 lesson: 2-byte nt stores defeat write-combining).
template <int MODE>
__global__ __launch_bounds__(256, 4) void gemm128(const bf16* __restrict__ Am,
                                                  const bf16* __restrict__ Bt,
                                                  bf16* __restrict__ C,
                                                  const float* __restrict__ bias) {
  __shared__ __align__(16) bf16 astg[2][8 * 512];
  __shared__ __align__(16) bf16 bstg[2][8 * 512];
  const int b = blockIdx.x;
  const int ct = (b & 7) * 4 + ((b >> 3) & 3);
  const int rt = b >> 5;
  const int tid = threadIdx.x, lane = tid & 63, wid = tid >> 6;
  const int wr = wid >> 1, wc = wid & 1;

  const bf16* gA[2];
  const bf16* gB[2];
  int lA[2], lB[2];
#pragma unroll
  for (int e = 0; e < 2; ++e) {
    const int mt = wid * 2 + e;
    gA[e] = Am + (size_t)(rt * 128 + mt * 16 + (lane & 15)) * 1024 + (lane >> 4) * 8;
    lA[e] = mt * 512;
    gB[e] = Bt + ((size_t)(ct * 8 + mt) * 32) * 512 + lane * 8;
    lB[e] = mt * 512;
  }
  f32x4 acc[4][4];
#pragma unroll
  for (int i = 0; i < 4; ++i)
#pragma unroll
    for (int j = 0; j < 4; ++j) acc[i][j] = (f32x4){0, 0, 0, 0};

#pragma unroll
  for (int e = 0; e < 2; ++e) {
    gload_lds16(gA[e], &astg[0][lA[e]]);
    gload_lds16(gB[e], &bstg[0][lB[e]]);
  }
  for (int it = 0; it < 32; ++it) {
    __syncthreads();
    if (it < 31) {
#pragma unroll
      for (int e = 0; e < 2; ++e) {
        gload_lds16(gA[e] + (it + 1) * 32, &astg[(it + 1) & 1][lA[e]]);
        gload_lds16(gB[e] + (size_t)(it + 1) * 512, &bstg[(it + 1) & 1][lB[e]]);
      }
    }
    const bf16* ab = astg[it & 1];
    const bf16* bb = bstg[it & 1];
    bf16x8 af[4], bfr[4];
#pragma unroll
    for (int i = 0; i < 4; ++i) af[i] = *(const bf16x8*)(ab + (wr * 4 + i) * 512 + lane * 8);
#pragma unroll
    for (int j = 0; j < 4; ++j) bfr[j] = *(const bf16x8*)(bb + (wc * 4 + j) * 512 + lane * 8);
#pragma unroll
    for (int i = 0; i < 4; ++i)
#pragma unroll
      for (int j = 0; j < 4; ++j)
        acc[i][j] = __builtin_amdgcn_mfma_f32_16x16x32_bf16(af[i], bfr[j], acc[i][j], 0, 0, 0);
  }
  // C/D layout: col=lane&15, row=(lane>>4)*4+r [m89-verified]
#pragma unroll
  for (int j = 0; j < 4; ++j) {
    const int col = ct * 128 + wc * 64 + j * 16 + (lane & 15);
    float bv = 0.f;
    if (MODE == 0) {
      const int rem = col & 63;
      bv = bias[(rem & 3) * HH + (col >> 6) * 16 + (rem >> 2)];
    }
#pragma unroll
    for (int i = 0; i < 4; ++i) {
      const int row0 = rt * 128 + wr * 64 + i * 16 + (lane >> 4) * 4;
#pragma unroll
      for (int r = 0; r < 4; ++r) {
        const int row = row0 + r;
        size_t idx;
        if (MODE == 0) idx = (size_t)row * NOUT + col;  // rows are t*NB+n
        else           idx = (size_t)(row >> 4) * (NOUT * 16) + (size_t)col * 16 + (row & 15);
        C[idx] = (bf16)(acc[i][j][r] + bv);
      }
    }
  }
}

// ---- per-step kernel (R17-proven: LDS staging + early-issue, single drain) --
#define STEP_SMEM 65536
__global__ __launch_bounds__(512, 4) void step_kernel(
    const bf16* __restrict__ Aop_cur, bf16* __restrict__ Aop_nxt,
    const bf16* __restrict__ Wh_t, const bf16* __restrict__ xWx2,
    const bf16* __restrict__ G2, const float* __restrict__ s_cur,
    float* __restrict__ s_nxt, float* __restrict__ s_zro,
    const bf16* __restrict__ A_bf, float* __restrict__ c_ws,
    float* __restrict__ out, const int t) {
  __shared__ __align__(16) char smem[STEP_SMEM];
  __shared__ float w_sh[512];
  bf16* astg = (bf16*)smem;   // [kg][mt*8+ks][512] = 64 KB (one-shot)
  float* red = (float*)smem;  // union after GEMM

  const int b = blockIdx.x;
  const int xcd = b & 7;
  const int ht = xcd * 8 + ((b >> 3) & 7);  // [0,64)
  const int rt = b >> 6;                    // [0,8)
  const int tid = threadIdx.x, lane = tid & 63, wid = tid >> 6;
  const int kg = wid >> 1, ow = wid & 1;
  const int nloc = tid >> 4, hl = tid & 15;
  const int n = rt * 32 + nloc, h = ht * 16 + hl;

  // score read FIRST (its waitcnt then only covers this one load)
  float ss = s_cur[n * 16 + hl];

  // one-shot A staging: wave wid issues tiles tau = wid*8+e
#pragma unroll
  for (int e = 0; e < 8; ++e) {
    const int tau = wid * 8 + e;
    const int tkg = tau >> 4, tmt = (tau >> 3) & 1, tks = tau & 7;
    const bf16* src = Aop_cur +
        (size_t)(rt * 32 + tmt * 16 + (lane & 15)) * 1024 +
        tkg * 256 + tks * 32 + (lane >> 4) * 8;
    gload_lds16(src, astg + tkg * 8192 + (tmt * 8 + tks) * 512);
  }

  // early-issue (T14): G2 block + xWx2 + c_ws + first B fragments -- all
  // independent of LDS; latency hides under softmax + barrier drain.
  bf16x8 gq[8];
  {
    const bf16* Gp = G2 + (size_t)n * (NOUT * 16) + (size_t)(ht * 64 + hl * 4) * 16;
#pragma unroll
    for (int e = 0; e < 8; ++e) gq[e] = *(const bf16x8*)(Gp + e * 8);
  }
  const bf16x4 xv = *(const bf16x4*)(xWx2 + (size_t)t * (NB * NOUT) +
                                     (size_t)n * NOUT + ht * 64 + hl * 4);
  const float cold = c_ws[(n << 10) + h];
  const bf16* gB0 = Wh_t + ((size_t)(ht * 4 + ow * 2 + 0) * 32 + kg * 8) * 512 + lane * 8;
  const bf16* gB1 = Wh_t + ((size_t)(ht * 4 + ow * 2 + 1) * 32 + kg * 8) * 512 + lane * 8;
  bf16x8 bc0 = *(const bf16x8*)gB0;
  bf16x8 bc1 = *(const bf16x8*)gB1;
  // zero the t+2 score buffer (32 B per wg)
  if (tid < 8) s_zro[b * 8 + tid] = 0.f;

  // softmax over p within 16-lane groups
  {
    ss *= 0.03125f;  // 1/sqrt(1024)
    float m = ss;
    SWZ_MAX(m, 0x041F); SWZ_MAX(m, 0x081F); SWZ_MAX(m, 0x101F); SWZ_MAX(m, 0x201F);
    const float e = expf(ss - m);
    float su = e;
    SWZ_ADD(su, 0x041F); SWZ_ADD(su, 0x081F); SWZ_ADD(su, 0x101F); SWZ_ADD(su, 0x201F);
    w_sh[tid] = e / su;
  }
  __syncthreads();  // single drain: staging + all early-issue loads landed

  // ---- GEMM: wave (kg,ow) does K=256, 8 ks x 4 MFMA, B rolling 1-ahead ----
  f32x4 a00 = {0, 0, 0, 0}, a01 = {0, 0, 0, 0}, a10 = {0, 0, 0, 0}, a11 = {0, 0, 0, 0};
  {
    const bf16* ab = astg + kg * 8192;
    __builtin_amdgcn_s_setprio(1);
#pragma unroll
    for (int ks = 0; ks < 8; ++ks) {
      bf16x8 bn0, bn1;
      if (ks < 7) {
        bn0 = *(const bf16x8*)(gB0 + (ks + 1) * 512);
        bn1 = *(const bf16x8*)(gB1 + (ks + 1) * 512);
      }
      const bf16x8 f0 = *(const bf16x8*)(ab + ks * 512 + lane * 8);
      const bf16x8 f1 = *(const bf16x8*)(ab + (8 + ks) * 512 + lane * 8);
      a00 = __builtin_amdgcn_mfma_f32_16x16x32_bf16(f0, bc0, a00, 0, 0, 0);
      a01 = __builtin_amdgcn_mfma_f32_16x16x32_bf16(f0, bc1, a01, 0, 0, 0);
      a10 = __builtin_amdgcn_mfma_f32_16x16x32_bf16(f1, bc0, a10, 0, 0, 0);
      a11 = __builtin_amdgcn_mfma_f32_16x16x32_bf16(f1, bc1, a11, 0, 0, 0);
      if (ks < 7) { bc0 = bn0; bc1 = bn1; }
    }
    __builtin_amdgcn_s_setprio(0);
  }
  __syncthreads();  // astg dead -> red live

  // fragment -> red[(kg*64 + c)*36 + nn]; c = ow*32 + j*16 + (lane&15)
  {
    const int cb = kg * 64 + ow * 32 + (lane & 15);
    const int nb = (lane >> 4) * 4;
    *(f32x4*)&red[(cb)*36 + nb] = a00;
    *(f32x4*)&red[(cb + 16) * 36 + nb] = a01;
    *(f32x4*)&red[(cb)*36 + nb + 16] = a10;
    *(f32x4*)&red[(cb + 16) * 36 + nb + 16] = a11;
  }
  __syncthreads();

  // ---- cell ----
  f32x4 gv = {0, 0, 0, 0};
#pragma unroll
  for (int k2 = 0; k2 < 4; ++k2)
#pragma unroll
    for (int g = 0; g < 4; ++g) gv[g] += red[(k2 * 64 + hl * 4 + g) * 36 + nloc];
  // attn term: gv[g] += sum_p w[p] * G2[n][hl*4+g][p]
#pragma unroll
  for (int g = 0; g < 4; ++g) {
    float a0 = 0.f;
#pragma unroll
    for (int p = 0; p < 8; ++p) a0 = fmaf(w_sh[nloc * 16 + p], (float)gq[g * 2][p], a0);
#pragma unroll
    for (int p = 0; p < 8; ++p) a0 = fmaf(w_sh[nloc * 16 + 8 + p], (float)gq[g * 2 + 1][p], a0);
    gv[g] += a0;
  }
  const float ai = gv[0] + (float)xv[0];
  const float af = gv[1] + (float)xv[1];
  const float ao = gv[2] + (float)xv[2];
  const float ag = gv[3] + (float)xv[3];
  const float si = 1.f / (1.f + expf(-ai));
  const float sf = 1.f / (1.f + expf(-af));
  const float so = 1.f / (1.f + expf(-ao));
  const float cn = sf * cold + si * tanhf(ag);
  const float hn = so * tanhf(cn);
  c_ws[(n << 10) + h] = cn;
  __builtin_nontemporal_store(hn, &out[((size_t)n * TS + t) * HH + h]);
  Aop_nxt[(n << 10) + h] = (bf16)hn;

  if (t < TS - 1) {  // next-step score partials: LDS transpose + atomicAdd
    __syncthreads();  // red gate-reads done -> reuse as transpose buffer
    const bf16* arow = A_bf + ((size_t)n * HH + h) * 16;
    const bf16x8 av0 = *(const bf16x8*)arow;
    const bf16x8 av1 = *(const bf16x8*)(arow + 8);
#pragma unroll
    for (int r = 0; r < 8; ++r) {
      red[(nloc * 16 + r) * 17 + hl] = hn * (float)av0[r];
      red[(nloc * 16 + 8 + r) * 17 + hl] = hn * (float)av1[r];
    }
    __syncthreads();
    const float* r2 = &red[(nloc * 16 + hl) * 17];  // p = hl, sum over 16 h
    float s = 0.f;
#pragma unroll
    for (int q = 0; q < 16; ++q) s += r2[q];
    atomicAdd(&s_nxt[n * 16 + hl], s);  // device-scope [m20]
  }
}

// ---------------------------------------------------------------------------
// ws layout (bytes), ~245 MB of 256 MiB:
//   [0, 8388608)             Wh_t   bf16 tiles (1024x4096, cx cols)
//   [8388608, 16777216)      Wat_t  bf16 tiles (1024x4096, cx cols)
//   [16777216, 25165824)     At     bf16 (4096x1024)
//   [25165824, 33554432)     A_bf   bf16 (256x1024x16)
//   [33554432, 167772160)    xWx2   bf16 [t][n][cx] (+bias)
//   [167772160, 201326592)   G2     bf16 [n][cx][p]
//   [201326592, 234881024)   x_bf   bf16 [t][n][d]   [transient]
//   [234881024, 243269632)   Wxt    bf16 tiles        [transient]
//   [243269632, 243793920)   Aop0   bf16 (256x1024)
//   [243793920, 244318208)   Aop1   bf16 (256x1024)
//   [244318208, 244334592)   s0     f32 (256x16)
//   [244334592, 244350976)   s1     f32 (256x16)  [memset 0 each call]
//   [244350976, 244367360)   s2     f32 (256x16)  [zeroed by step t=0]
//   [244367360, 245415936)   c_ws   f32 (256x1024)
// ---------------------------------------------------------------------------
extern "C" void kernel_launch(void* const* d_in, const int* in_sizes, int n_in,
                              void* d_out, int out_size, void* d_ws, size_t ws_size,
                              hipStream_t stream) {
  const float* x     = (const float*)d_in[0];
  const float* A     = (const float*)d_in[1];
  const float* Wx    = (const float*)d_in[2];
  const float* Wh    = (const float*)d_in[3];
  const float* Wattn = (const float*)d_in[4];
  const float* bias  = (const float*)d_in[5];
  float* out = (float*)d_out;
  char* ws = (char*)d_ws;
  bf16* Wh_t   = (bf16*)(ws + 0);
  bf16* Wat_t  = (bf16*)(ws + 8388608);
  bf16* At     = (bf16*)(ws + 16777216);
  bf16* A_bf   = (bf16*)(ws + 25165824);
  bf16* xWx2   = (bf16*)(ws + 33554432);
  bf16* G2     = (bf16*)(ws + 167772160);
  bf16* x_bf   = (bf16*)(ws + 201326592);
  bf16* Wxt    = (bf16*)(ws + 234881024);
  bf16* Aop0   = (bf16*)(ws + 243269632);
  bf16* Aop1   = (bf16*)(ws + 243793920);
  float* s0    = (float*)(ws + 244318208);
  float* s1    = (float*)(ws + 244334592);
  float* s2    = (float*)(ws + 244350976);
  float* c_ws  = (float*)(ws + 244367360);

  hipMemsetAsync(s1, 0, 16384, stream);
  convert_x<<<8192, 256, 0, stream>>>(x, x_bf);
  prep_A<<<256, 1024, 0, stream>>>(A, A_bf, At, c_ws, Aop0, s0);
  convert_wt2<<<128, 256, 0, stream>>>(Wx, Wxt);
  convert_wt2<<<128, 256, 0, stream>>>(Wh, Wh_t);
  convert_wt2<<<128, 256, 0, stream>>>(Wattn, Wat_t);
  gemm128<0><<<4096, 256, 0, stream>>>(x_bf, Wxt, xWx2, bias);  // x@Wx + bias
  gemm128<1><<<1024, 256, 0, stream>>>(At, Wat_t, G2, nullptr); // G2 = A^T@Wattn
  for (int t = 0; t < TS; ++t) {
    float* scur = (t % 3 == 0) ? s0 : (t % 3 == 1) ? s1 : s2;
    float* snxt = (t % 3 == 0) ? s1 : (t % 3 == 1) ? s2 : s0;
    float* szro = (t % 3 == 0) ? s2 : (t % 3 == 1) ? s0 : s1;
    step_kernel<<<512, 512, 0, stream>>>((t & 1) ? Aop1 : Aop0,
                                         (t & 1) ? Aop0 : Aop1, Wh_t, xWx2,
                                         G2, scur, snxt, szro, A_bf, c_ws,
                                         out, t);
  }
}

// Round 20
// 1299.608 us; speedup vs baseline: 1.1440x; 1.0425x over previous
//
#include <hip/hip_runtime.h>

typedef __bf16 bf16;
typedef bf16 bf16x8 __attribute__((ext_vector_type(8)));
typedef bf16 bf16x4 __attribute__((ext_vector_type(4)));
typedef float f32x4 __attribute__((ext_vector_type(4)));

#define NB 256
#define TS 64
#define DD 1024
#define HH 1024
#define NOUT 4096

// Column permutation (all weight/preact tensors): cx = (h>>4)*64 + (h&15)*4 + g
// (original col co = g*1024 + h). wg "ht" owns cx in [ht*64,+64) = 16 h x 4
// gates; cell thread (n,hl) reads its 4 gates as ONE bf16x4.
// Fragment tiles: 16col x 32k of 512 bf16; element (l,j): col=base+(l&15),
// k=kbase+(l>>4)*8+j (mfma_16x16x32 operand layout; linear LDS staging).
// Layouts: x_bf [t][n][d]; xWx2 [t][n][cx] bf16 +bias; G2 [n][cx][p].

static __device__ __forceinline__ void gload_lds16(const void* g, void* l) {
  __builtin_amdgcn_global_load_lds(
      (const __attribute__((address_space(1))) void*)g,
      (__attribute__((address_space(3))) void*)l, 16, 0, 0);
}

#define SWZ_ADD(v, imm) \
  (v) += __int_as_float(__builtin_amdgcn_ds_swizzle(__float_as_int(v), imm))
#define SWZ_MAX(v, imm) \
  (v) = fmaxf(v, __int_as_float(__builtin_amdgcn_ds_swizzle(__float_as_int(v), imm)))

// ---- one-time converts ------------------------------------------------------
// x (f32 [n][t][d]) -> x_bf (bf16 [t][n][d]).
__global__ __launch_bounds__(256) void convert_x(const float* __restrict__ x,
                                                 bf16* __restrict__ xb) {
  const int gid = blockIdx.x * 256 + threadIdx.x;
  const int t = gid >> 15;
  const int rem = gid & 32767;
  const int n = rem >> 7;
  const int d = (rem & 127) * 8;
  const float* src = x + ((size_t)n * TS + t) * DD + d;
  bf16x8 v;
#pragma unroll
  for (int j = 0; j < 8; ++j) v[j] = (bf16)src[j];
  *(bf16x8*)(xb + (size_t)gid * 8) = v;
}

// One pass over A: emits A_bf, At, h0/c0, Aop0, step-0 scores s0.
__global__ __launch_bounds__(1024) void prep_A(const float* __restrict__ A,
                                               bf16* __restrict__ A_bf,
                                               bf16* __restrict__ At,
                                               float* __restrict__ c_ws,
                                               bf16* __restrict__ Aop0,
                                               float* __restrict__ s0) {
  __shared__ float lt[1024 * 17];
  __shared__ float h_sh[1024];
  __shared__ float scA[16], scB[16];
  const int n = (blockIdx.x & 7) * 32 + (blockIdx.x >> 3);
  const int u = threadIdx.x;
  const float* ar = A + ((size_t)n * HH + u) * 16;
  float a[16];
#pragma unroll
  for (int q = 0; q < 4; ++q) {
    const f32x4 v = *(const f32x4*)(ar + q * 4);
#pragma unroll
    for (int r = 0; r < 4; ++r) {
      a[q * 4 + r] = v[r];
      lt[u * 17 + q * 4 + r] = v[r];
    }
  }
  {
    bf16x8 b0, b1;
#pragma unroll
    for (int j = 0; j < 8; ++j) { b0[j] = (bf16)a[j]; b1[j] = (bf16)a[8 + j]; }
    bf16* abf = A_bf + ((size_t)n * HH + u) * 16;
    *(bf16x8*)abf = b0;
    *(bf16x8*)(abf + 8) = b1;
  }
  float h0 = 0.f;
#pragma unroll
  for (int p = 0; p < 16; ++p) h0 += a[p];
  h0 *= 0.0625f;
  c_ws[(n << 10) + u] = h0;
  h_sh[u] = h0;
  Aop0[(n << 10) + u] = (bf16)h0;
  __syncthreads();
  {
    const int p = u >> 6, seg = u & 63;
    bf16x8 o0, o1;
#pragma unroll
    for (int j = 0; j < 8; ++j) {
      o0[j] = (bf16)lt[(seg * 16 + j) * 17 + p];
      o1[j] = (bf16)lt[(seg * 16 + 8 + j) * 17 + p];
    }
    bf16* dst = At + (size_t)(n * 16 + p) * 1024 + seg * 16;
    *(bf16x8*)dst = o0;
    *(bf16x8*)(dst + 8) = o1;
  }
  {
    const int lane = u & 63, w = u >> 6;
    float s = 0.f;
#pragma unroll
    for (int i = 0; i < 16; ++i) {
      const int idx = lane + 64 * i;
      s = fmaf(h_sh[idx], lt[idx * 17 + w], s);
    }
    SWZ_ADD(s, 0x041F); SWZ_ADD(s, 0x081F); SWZ_ADD(s, 0x101F);
    SWZ_ADD(s, 0x201F); SWZ_ADD(s, 0x401F);
    if (lane == 0) scA[w] = s;
    else if (lane == 32) scB[w] = s;
  }
  __syncthreads();
  if (u < 16) s0[n * 16 + u] = scA[u] + scB[u];
}

// Wx/Wh/Wattn (each 1024 x 4096 f32) -> cx-permuted fragment tiles, coalesced
// reads; ONE launch for all three (grid 384: w = b>>7 selects matrix).
__global__ __launch_bounds__(256) void convert_wt3(const float* __restrict__ W0,
                                                   const float* __restrict__ W1,
                                                   const float* __restrict__ W2,
                                                   bf16* __restrict__ T0,
                                                   bf16* __restrict__ T1,
                                                   bf16* __restrict__ T2) {
  __shared__ bf16 lb[8 * 4096];  // 64 KB: [row j][cx]
  const int w = blockIdx.x >> 7;
  const int kb = blockIdx.x & 127;  // k rows [kb*8, kb*8+8)
  const float* W = (w == 0) ? W0 : (w == 1) ? W1 : W2;
  bf16* Wt = (w == 0) ? T0 : (w == 1) ? T1 : T2;
  const int kt = kb >> 2, group = kb & 3;
  const int tid = threadIdx.x;
#pragma unroll
  for (int qq = 0; qq < 32; ++qq) {
    const int chunk = qq * 256 + tid;
    const int row = chunk >> 10;
    const int colb = (chunk & 1023) * 4;
    const f32x4 v = *(const f32x4*)(W + (size_t)(kb * 8 + row) * NOUT + colb);
#pragma unroll
    for (int e = 0; e < 4; ++e) {
      const int co = colb + e;
      const int hh = co & 1023, g = co >> 10;
      const int cx = (hh >> 4) * 64 + (hh & 15) * 4 + g;
      lb[row * 4096 + cx] = (bf16)v[e];
    }
  }
  __syncthreads();
  const int tau = tid;  // all 256 taus
  bf16* wbase = Wt + (size_t)(tau * 32 + kt) * 512 + group * 16 * 8;
#pragma unroll
  for (int c = 0; c < 16; ++c) {
    const int cx = tau * 16 + c;
    bf16x8 o;
#pragma unroll
    for (int j = 0; j < 8; ++j) o[j] = lb[j * 4096 + cx];
    *(bf16x8*)(wbase + c * 8) = o;
  }
}

// ---- 128x128 / BK=32 GEMM (m97 structure), bf16 out, ct-pinned swizzle ------
// MODE 0 (4096 wgs, rows = t*NB+n): plain row-major [t][n][col], bias folded.
// MODE 1 (1024 wgs, rows = n*16+p): write [n][col][p].
template <int MODE>
__global__ __launch_bounds__(256, 4) void gemm128(const bf16* __restrict__ Am,
                                                  const bf16* __restrict__ Bt,
                                                  bf16* __restrict__ C,
                                                  const float* __restrict__ bias) {
  __shared__ __align__(16) bf16 astg[2][8 * 512];
  __shared__ __align__(16) bf16 bstg[2][8 * 512];
  const int b = blockIdx.x;
  const int ct = (b & 7) * 4 + ((b >> 3) & 3);
  const int rt = b >> 5;
  const int tid = threadIdx.x, lane = tid & 63, wid = tid >> 6;
  const int wr = wid >> 1, wc = wid & 1;

  const bf16* gA[2];
  const bf16* gB[2];
  int lA[2], lB[2];
#pragma unroll
  for (int e = 0; e < 2; ++e) {
    const int mt = wid * 2 + e;
    gA[e] = Am + (size_t)(rt * 128 + mt * 16 + (lane & 15)) * 1024 + (lane >> 4) * 8;
    lA[e] = mt * 512;
    gB[e] = Bt + ((size_t)(ct * 8 + mt) * 32) * 512 + lane * 8;
    lB[e] = mt * 512;
  }
  f32x4 acc[4][4];
#pragma unroll
  for (int i = 0; i < 4; ++i)
#pragma unroll
    for (int j = 0; j < 4; ++j) acc[i][j] = (f32x4){0, 0, 0, 0};

#pragma unroll
  for (int e = 0; e < 2; ++e) {
    gload_lds16(gA[e], &astg[0][lA[e]]);
    gload_lds16(gB[e], &bstg[0][lB[e]]);
  }
  for (int it = 0; it < 32; ++it) {
    __syncthreads();
    if (it < 31) {
#pragma unroll
      for (int e = 0; e < 2; ++e) {
        gload_lds16(gA[e] + (it + 1) * 32, &astg[(it + 1) & 1][lA[e]]);
        gload_lds16(gB[e] + (size_t)(it + 1) * 512, &bstg[(it + 1) & 1][lB[e]]);
      }
    }
    const bf16* ab = astg[it & 1];
    const bf16* bb = bstg[it & 1];
    bf16x8 af[4], bfr[4];
#pragma unroll
    for (int i = 0; i < 4; ++i) af[i] = *(const bf16x8*)(ab + (wr * 4 + i) * 512 + lane * 8);
#pragma unroll
    for (int j = 0; j < 4; ++j) bfr[j] = *(const bf16x8*)(bb + (wc * 4 + j) * 512 + lane * 8);
#pragma unroll
    for (int i = 0; i < 4; ++i)
#pragma unroll
      for (int j = 0; j < 4; ++j)
        acc[i][j] = __builtin_amdgcn_mfma_f32_16x16x32_bf16(af[i], bfr[j], acc[i][j], 0, 0, 0);
  }
  // C/D layout: col=lane&15, row=(lane>>4)*4+r [m89-verified]
#pragma unroll
  for (int j = 0; j < 4; ++j) {
    const int col = ct * 128 + wc * 64 + j * 16 + (lane & 15);
    float bv = 0.f;
    if (MODE == 0) {
      const int rem = col & 63;
      bv = bias[(rem & 3) * HH + (col >> 6) * 16 + (rem >> 2)];
    }
#pragma unroll
    for (int i = 0; i < 4; ++i) {
      const int row0 = rt * 128 + wr * 64 + i * 16 + (lane >> 4) * 4;
#pragma unroll
      for (int r = 0; r < 4; ++r) {
        const int row = row0 + r;
        size_t idx;
        if (MODE == 0) idx = (size_t)row * NOUT + col;  // rows are t*NB+n
        else           idx = (size_t)(row >> 4) * (NOUT * 16) + (size_t)col * 16 + (row & 15);
        C[idx] = (bf16)(acc[i][j][r] + bv);
      }
    }
  }
}

// ---- per-step kernel (R17 structure + 2-deep B prefetch) --------------------
#define STEP_SMEM 65536
__global__ __launch_bounds__(512, 4) void step_kernel(
    const bf16* __restrict__ Aop_cur, bf16* __restrict__ Aop_nxt,
    const bf16* __restrict__ Wh_t, const bf16* __restrict__ xWx2,
    const bf16* __restrict__ G2, const float* __restrict__ s_cur,
    float* __restrict__ s_nxt, float* __restrict__ s_zro,
    const bf16* __restrict__ A_bf, float* __restrict__ c_ws,
    float* __restrict__ out, const int t) {
  __shared__ __align__(16) char smem[STEP_SMEM];
  __shared__ float w_sh[512];
  bf16* astg = (bf16*)smem;   // [kg][mt*8+ks][512] = 64 KB (one-shot)
  float* red = (float*)smem;  // union after GEMM

  const int b = blockIdx.x;
  const int xcd = b & 7;
  const int ht = xcd * 8 + ((b >> 3) & 7);  // [0,64)
  const int rt = b >> 6;                    // [0,8)
  const int tid = threadIdx.x, lane = tid & 63, wid = tid >> 6;
  const int kg = wid >> 1, ow = wid & 1;
  const int nloc = tid >> 4, hl = tid & 15;
  const int n = rt * 32 + nloc, h = ht * 16 + hl;

  // score read FIRST (its waitcnt then only covers this one load)
  float ss = s_cur[n * 16 + hl];

  // one-shot A staging: wave wid issues tiles tau = wid*8+e
#pragma unroll
  for (int e = 0; e < 8; ++e) {
    const int tau = wid * 8 + e;
    const int tkg = tau >> 4, tmt = (tau >> 3) & 1, tks = tau & 7;
    const bf16* src = Aop_cur +
        (size_t)(rt * 32 + tmt * 16 + (lane & 15)) * 1024 +
        tkg * 256 + tks * 32 + (lane >> 4) * 8;
    gload_lds16(src, astg + tkg * 8192 + (tmt * 8 + tks) * 512);
  }

  // early-issue (T14): G2 block + xWx2 + c_ws + first 2 B fragments
  bf16x8 gq[8];
  {
    const bf16* Gp = G2 + (size_t)n * (NOUT * 16) + (size_t)(ht * 64 + hl * 4) * 16;
#pragma unroll
    for (int e = 0; e < 8; ++e) gq[e] = *(const bf16x8*)(Gp + e * 8);
  }
  const bf16x4 xv = *(const bf16x4*)(xWx2 + (size_t)t * (NB * NOUT) +
                                     (size_t)n * NOUT + ht * 64 + hl * 4);
  const float cold = c_ws[(n << 10) + h];
  const bf16* gB0 = Wh_t + ((size_t)(ht * 4 + ow * 2 + 0) * 32 + kg * 8) * 512 + lane * 8;
  const bf16* gB1 = Wh_t + ((size_t)(ht * 4 + ow * 2 + 1) * 32 + kg * 8) * 512 + lane * 8;
  bf16x8 bc0 = *(const bf16x8*)gB0;
  bf16x8 bc1 = *(const bf16x8*)gB1;
  bf16x8 bd0 = *(const bf16x8*)(gB0 + 512);
  bf16x8 bd1 = *(const bf16x8*)(gB1 + 512);
  // zero the t+2 score buffer (32 B per wg)
  if (tid < 8) s_zro[b * 8 + tid] = 0.f;

  // softmax over p within 16-lane groups
  {
    ss *= 0.03125f;  // 1/sqrt(1024)
    float m = ss;
    SWZ_MAX(m, 0x041F); SWZ_MAX(m, 0x081F); SWZ_MAX(m, 0x101F); SWZ_MAX(m, 0x201F);
    const float e = expf(ss - m);
    float su = e;
    SWZ_ADD(su, 0x041F); SWZ_ADD(su, 0x081F); SWZ_ADD(su, 0x101F); SWZ_ADD(su, 0x201F);
    w_sh[tid] = e / su;
  }
  __syncthreads();  // single drain: staging + all early-issue loads landed

  // ---- GEMM: wave (kg,ow) does K=256, 8 ks x 4 MFMA, B rolling 2-ahead ----
  f32x4 a00 = {0, 0, 0, 0}, a01 = {0, 0, 0, 0}, a10 = {0, 0, 0, 0}, a11 = {0, 0, 0, 0};
  {
    const bf16* ab = astg + kg * 8192;
    __builtin_amdgcn_s_setprio(1);
#pragma unroll
    for (int ks = 0; ks < 8; ++ks) {
      bf16x8 bn0, bn1;
      if (ks < 6) {
        bn0 = *(const bf16x8*)(gB0 + (ks + 2) * 512);
        bn1 = *(const bf16x8*)(gB1 + (ks + 2) * 512);
      }
      const bf16x8 f0 = *(const bf16x8*)(ab + ks * 512 + lane * 8);
      const bf16x8 f1 = *(const bf16x8*)(ab + (8 + ks) * 512 + lane * 8);
      a00 = __builtin_amdgcn_mfma_f32_16x16x32_bf16(f0, bc0, a00, 0, 0, 0);
      a01 = __builtin_amdgcn_mfma_f32_16x16x32_bf16(f0, bc1, a01, 0, 0, 0);
      a10 = __builtin_amdgcn_mfma_f32_16x16x32_bf16(f1, bc0, a10, 0, 0, 0);
      a11 = __builtin_amdgcn_mfma_f32_16x16x32_bf16(f1, bc1, a11, 0, 0, 0);
      bc0 = bd0; bc1 = bd1;
      if (ks < 6) { bd0 = bn0; bd1 = bn1; }
    }
    __builtin_amdgcn_s_setprio(0);
  }
  __syncthreads();  // astg dead -> red live

  // fragment -> red[(kg*64 + c)*36 + nn]; c = ow*32 + j*16 + (lane&15)
  {
    const int cb = kg * 64 + ow * 32 + (lane & 15);
    const int nb = (lane >> 4) * 4;
    *(f32x4*)&red[(cb)*36 + nb] = a00;
    *(f32x4*)&red[(cb + 16) * 36 + nb] = a01;
    *(f32x4*)&red[(cb)*36 + nb + 16] = a10;
    *(f32x4*)&red[(cb + 16) * 36 + nb + 16] = a11;
  }
  __syncthreads();

  // ---- cell ----
  f32x4 gv = {0, 0, 0, 0};
#pragma unroll
  for (int k2 = 0; k2 < 4; ++k2)
#pragma unroll
    for (int g = 0; g < 4; ++g) gv[g] += red[(k2 * 64 + hl * 4 + g) * 36 + nloc];
  // attn term: gv[g] += sum_p w[p] * G2[n][hl*4+g][p]
#pragma unroll
  for (int g = 0; g < 4; ++g) {
    float a0 = 0.f;
#pragma unroll
    for (int p = 0; p < 8; ++p) a0 = fmaf(w_sh[nloc * 16 + p], (float)gq[g * 2][p], a0);
#pragma unroll
    for (int p = 0; p < 8; ++p) a0 = fmaf(w_sh[nloc * 16 + 8 + p], (float)gq[g * 2 + 1][p], a0);
    gv[g] += a0;
  }
  const float ai = gv[0] + (float)xv[0];
  const float af = gv[1] + (float)xv[1];
  const float ao = gv[2] + (float)xv[2];
  const float ag = gv[3] + (float)xv[3];
  const float si = 1.f / (1.f + expf(-ai));
  const float sf = 1.f / (1.f + expf(-af));
  const float so = 1.f / (1.f + expf(-ao));
  const float cn = sf * cold + si * tanhf(ag);
  const float hn = so * tanhf(cn);
  c_ws[(n << 10) + h] = cn;
  __builtin_nontemporal_store(hn, &out[((size_t)n * TS + t) * HH + h]);
  Aop_nxt[(n << 10) + h] = (bf16)hn;

  if (t < TS - 1) {  // next-step score partials: LDS transpose + atomicAdd
    __syncthreads();  // red gate-reads done -> reuse as transpose buffer
    const bf16* arow = A_bf + ((size_t)n * HH + h) * 16;
    const bf16x8 av0 = *(const bf16x8*)arow;
    const bf16x8 av1 = *(const bf16x8*)(arow + 8);
#pragma unroll
    for (int r = 0; r < 8; ++r) {
      red[(nloc * 16 + r) * 17 + hl] = hn * (float)av0[r];
      red[(nloc * 16 + 8 + r) * 17 + hl] = hn * (float)av1[r];
    }
    __syncthreads();
    const float* r2 = &red[(nloc * 16 + hl) * 17];  // p = hl, sum over 16 h
    float s = 0.f;
#pragma unroll
    for (int q = 0; q < 16; ++q) s += r2[q];
    atomicAdd(&s_nxt[n * 16 + hl], s);  // device-scope [m20]
  }
}

// ---------------------------------------------------------------------------
// ws layout (bytes), ~245 MB of 256 MiB:
//   [0, 8388608)             Wh_t   bf16 tiles (1024x4096, cx cols)
//   [8388608, 16777216)      Wat_t  bf16 tiles (1024x4096, cx cols)
//   [16777216, 25165824)     At     bf16 (4096x1024)
//   [25165824, 33554432)     A_bf   bf16 (256x1024x16)
//   [33554432, 167772160)    xWx2   bf16 [t][n][cx] (+bias)
//   [167772160, 201326592)   G2     bf16 [n][cx][p]
//   [201326592, 234881024)   x_bf   bf16 [t][n][d]   [transient]
//   [234881024, 243269632)   Wxt    bf16 tiles        [transient]
//   [243269632, 243793920)   Aop0   bf16 (256x1024)
//   [243793920, 244318208)   Aop1   bf16 (256x1024)
//   [244318208, 244334592)   s0     f32 (256x16)
//   [244334592, 244350976)   s1     f32 (256x16)  [memset 0 each call]
//   [244350976, 244367360)   s2     f32 (256x16)  [zeroed by step t=0]
//   [244367360, 245415936)   c_ws   f32 (256x1024)
// ---------------------------------------------------------------------------
extern "C" void kernel_launch(void* const* d_in, const int* in_sizes, int n_in,
                              void* d_out, int out_size, void* d_ws, size_t ws_size,
                              hipStream_t stream) {
  const float* x     = (const float*)d_in[0];
  const float* A     = (const float*)d_in[1];
  const float* Wx    = (const float*)d_in[2];
  const float* Wh    = (const float*)d_in[3];
  const float* Wattn = (const float*)d_in[4];
  const float* bias  = (const float*)d_in[5];
  float* out = (float*)d_out;
  char* ws = (char*)d_ws;
  bf16* Wh_t   = (bf16*)(ws + 0);
  bf16* Wat_t  = (bf16*)(ws + 8388608);
  bf16* At     = (bf16*)(ws + 16777216);
  bf16* A_bf   = (bf16*)(ws + 25165824);
  bf16* xWx2   = (bf16*)(ws + 33554432);
  bf16* G2     = (bf16*)(ws + 167772160);
  bf16* x_bf   = (bf16*)(ws + 201326592);
  bf16* Wxt    = (bf16*)(ws + 234881024);
  bf16* Aop0   = (bf16*)(ws + 243269632);
  bf16* Aop1   = (bf16*)(ws + 243793920);
  float* s0    = (float*)(ws + 244318208);
  float* s1    = (float*)(ws + 244334592);
  float* s2    = (float*)(ws + 244350976);
  float* c_ws  = (float*)(ws + 244367360);

  hipMemsetAsync(s1, 0, 16384, stream);
  convert_x<<<8192, 256, 0, stream>>>(x, x_bf);
  prep_A<<<256, 1024, 0, stream>>>(A, A_bf, At, c_ws, Aop0, s0);
  convert_wt3<<<384, 256, 0, stream>>>(Wx, Wh, Wattn, Wxt, Wh_t, Wat_t);
  gemm128<0><<<4096, 256, 0, stream>>>(x_bf, Wxt, xWx2, bias);  // x@Wx + bias
  gemm128<1><<<1024, 256, 0, stream>>>(At, Wat_t, G2, nullptr); // G2 = A^T@Wattn
  for (int t = 0; t < TS; ++t) {
    float* scur = (t % 3 == 0) ? s0 : (t % 3 == 1) ? s1 : s2;
    float* snxt = (t % 3 == 0) ? s1 : (t % 3 == 1) ? s2 : s0;
    float* szro = (t % 3 == 0) ? s2 : (t % 3 == 1) ? s0 : s1;
    step_kernel<<<512, 512, 0, stream>>>((t & 1) ? Aop1 : Aop0,
                                         (t & 1) ? Aop0 : Aop1, Wh_t, xWx2,
                                         G2, scur, snxt, szro, A_bf, c_ws,
                                         out, t);
  }
}

// Round 21
// 1294.964 us; speedup vs baseline: 1.1481x; 1.0036x over previous
//
#include <hip/hip_runtime.h>

typedef __bf16 bf16;
typedef bf16 bf16x8 __attribute__((ext_vector_type(8)));
typedef bf16 bf16x4 __attribute__((ext_vector_type(4)));
typedef float f32x4 __attribute__((ext_vector_type(4)));

#define NB 256
#define TS 64
#define DD 1024
#define HH 1024
#define NOUT 4096

// Column permutation (all weight/preact tensors): cx = (h>>4)*64 + (h&15)*4 + g
// (original col co = g*1024 + h). wg "ht" owns cx in [ht*64,+64) = 16 h x 4
// gates; cell thread (n,hl) reads its 4 gates as ONE bf16x4.
// Fragment tiles: 16col x 32k of 512 bf16; element (l,j): col=base+(l&15),
// k=kbase+(l>>4)*8+j (mfma_16x16x32 operand layout; linear LDS staging).
// Layouts: x_bf [t][n][d]; xWx2 [t][n][cx] bf16 +bias; G2 [n][cx][p].

static __device__ __forceinline__ void gload_lds16(const void* g, void* l) {
  __builtin_amdgcn_global_load_lds(
      (const __attribute__((address_space(1))) void*)g,
      (__attribute__((address_space(3))) void*)l, 16, 0, 0);
}

#define SWZ_ADD(v, imm) \
  (v) += __int_as_float(__builtin_amdgcn_ds_swizzle(__float_as_int(v), imm))
#define SWZ_MAX(v, imm) \
  (v) = fmaxf(v, __int_as_float(__builtin_amdgcn_ds_swizzle(__float_as_int(v), imm)))

// ---- one-time converts ------------------------------------------------------
// x (f32 [n][t][d]) -> x_bf (bf16 [t][n][d]).
__global__ __launch_bounds__(256) void convert_x(const float* __restrict__ x,
                                                 bf16* __restrict__ xb) {
  const int gid = blockIdx.x * 256 + threadIdx.x;
  const int t = gid >> 15;
  const int rem = gid & 32767;
  const int n = rem >> 7;
  const int d = (rem & 127) * 8;
  const float* src = x + ((size_t)n * TS + t) * DD + d;
  bf16x8 v;
#pragma unroll
  for (int j = 0; j < 8; ++j) v[j] = (bf16)src[j];
  *(bf16x8*)(xb + (size_t)gid * 8) = v;
}

// One pass over A: emits A_bf, At, h0/c0, Aop0, step-0 scores s0.
__global__ __launch_bounds__(1024) void prep_A(const float* __restrict__ A,
                                               bf16* __restrict__ A_bf,
                                               bf16* __restrict__ At,
                                               float* __restrict__ c_ws,
                                               bf16* __restrict__ Aop0,
                                               float* __restrict__ s0) {
  __shared__ float lt[1024 * 17];
  __shared__ float h_sh[1024];
  __shared__ float scA[16], scB[16];
  const int n = (blockIdx.x & 7) * 32 + (blockIdx.x >> 3);
  const int u = threadIdx.x;
  const float* ar = A + ((size_t)n * HH + u) * 16;
  float a[16];
#pragma unroll
  for (int q = 0; q < 4; ++q) {
    const f32x4 v = *(const f32x4*)(ar + q * 4);
#pragma unroll
    for (int r = 0; r < 4; ++r) {
      a[q * 4 + r] = v[r];
      lt[u * 17 + q * 4 + r] = v[r];
    }
  }
  {
    bf16x8 b0, b1;
#pragma unroll
    for (int j = 0; j < 8; ++j) { b0[j] = (bf16)a[j]; b1[j] = (bf16)a[8 + j]; }
    bf16* abf = A_bf + ((size_t)n * HH + u) * 16;
    *(bf16x8*)abf = b0;
    *(bf16x8*)(abf + 8) = b1;
  }
  float h0 = 0.f;
#pragma unroll
  for (int p = 0; p < 16; ++p) h0 += a[p];
  h0 *= 0.0625f;
  c_ws[(n << 10) + u] = h0;
  h_sh[u] = h0;
  Aop0[(n << 10) + u] = (bf16)h0;
  __syncthreads();
  {
    const int p = u >> 6, seg = u & 63;
    bf16x8 o0, o1;
#pragma unroll
    for (int j = 0; j < 8; ++j) {
      o0[j] = (bf16)lt[(seg * 16 + j) * 17 + p];
      o1[j] = (bf16)lt[(seg * 16 + 8 + j) * 17 + p];
    }
    bf16* dst = At + (size_t)(n * 16 + p) * 1024 + seg * 16;
    *(bf16x8*)dst = o0;
    *(bf16x8*)(dst + 8) = o1;
  }
  {
    const int lane = u & 63, w = u >> 6;
    float s = 0.f;
#pragma unroll
    for (int i = 0; i < 16; ++i) {
      const int idx = lane + 64 * i;
      s = fmaf(h_sh[idx], lt[idx * 17 + w], s);
    }
    SWZ_ADD(s, 0x041F); SWZ_ADD(s, 0x081F); SWZ_ADD(s, 0x101F);
    SWZ_ADD(s, 0x201F); SWZ_ADD(s, 0x401F);
    if (lane == 0) scA[w] = s;
    else if (lane == 32) scB[w] = s;
  }
  __syncthreads();
  if (u < 16) s0[n * 16 + u] = scA[u] + scB[u];
}

// Wx/Wh/Wattn -> cx-permuted fragment tiles, coalesced reads; one launch.
__global__ __launch_bounds__(256) void convert_wt3(const float* __restrict__ W0,
                                                   const float* __restrict__ W1,
                                                   const float* __restrict__ W2,
                                                   bf16* __restrict__ T0,
                                                   bf16* __restrict__ T1,
                                                   bf16* __restrict__ T2) {
  __shared__ bf16 lb[8 * 4096];  // 64 KB: [row j][cx]
  const int w = blockIdx.x >> 7;
  const int kb = blockIdx.x & 127;  // k rows [kb*8, kb*8+8)
  const float* W = (w == 0) ? W0 : (w == 1) ? W1 : W2;
  bf16* Wt = (w == 0) ? T0 : (w == 1) ? T1 : T2;
  const int kt = kb >> 2, group = kb & 3;
  const int tid = threadIdx.x;
#pragma unroll
  for (int qq = 0; qq < 32; ++qq) {
    const int chunk = qq * 256 + tid;
    const int row = chunk >> 10;
    const int colb = (chunk & 1023) * 4;
    const f32x4 v = *(const f32x4*)(W + (size_t)(kb * 8 + row) * NOUT + colb);
#pragma unroll
    for (int e = 0; e < 4; ++e) {
      const int co = colb + e;
      const int hh = co & 1023, g = co >> 10;
      const int cx = (hh >> 4) * 64 + (hh & 15) * 4 + g;
      lb[row * 4096 + cx] = (bf16)v[e];
    }
  }
  __syncthreads();
  const int tau = tid;  // all 256 taus
  bf16* wbase = Wt + (size_t)(tau * 32 + kt) * 512 + group * 16 * 8;
#pragma unroll
  for (int c = 0; c < 16; ++c) {
    const int cx = tau * 16 + c;
    bf16x8 o;
#pragma unroll
    for (int j = 0; j < 8; ++j) o[j] = lb[j * 4096 + cx];
    *(bf16x8*)(wbase + c * 8) = o;
  }
}

// ---- 128x128 / BK=32 GEMM (m97 structure), bf16 out -------------------------
// MODE 0 (4096 wgs, rows = t*NB+n): RT-PINNED swizzle (each XCD owns a 4 MB
//        A row-slice, L2-resident; B panels sequentially hot; output writes
//        are plain row-major so rt-pinning is write-safe post-R16).
// MODE 1 (1024 wgs, rows = n*16+p): ct-pinned swizzle, writes [n][col][p].
template <int MODE>
__global__ __launch_bounds__(256, 4) void gemm128(const bf16* __restrict__ Am,
                                                  const bf16* __restrict__ Bt,
                                                  bf16* __restrict__ C,
                                                  const float* __restrict__ bias) {
  __shared__ __align__(16) bf16 astg[2][8 * 512];
  __shared__ __align__(16) bf16 bstg[2][8 * 512];
  const int b = blockIdx.x;
  int rt, ct;
  if (MODE == 0) {  // 4096 wgs: rt in [0,128), ct in [0,32)
    rt = (b & 7) * 16 + ((b >> 3) & 15);
    ct = b >> 7;
  } else {          // 1024 wgs: rt in [0,32), ct in [0,32)
    ct = (b & 7) * 4 + ((b >> 3) & 3);
    rt = b >> 5;
  }
  const int tid = threadIdx.x, lane = tid & 63, wid = tid >> 6;
  const int wr = wid >> 1, wc = wid & 1;

  const bf16* gA[2];
  const bf16* gB[2];
  int lA[2], lB[2];
#pragma unroll
  for (int e = 0; e < 2; ++e) {
    const int mt = wid * 2 + e;
    gA[e] = Am + (size_t)(rt * 128 + mt * 16 + (lane & 15)) * 1024 + (lane >> 4) * 8;
    lA[e] = mt * 512;
    gB[e] = Bt + ((size_t)(ct * 8 + mt) * 32) * 512 + lane * 8;
    lB[e] = mt * 512;
  }
  f32x4 acc[4][4];
#pragma unroll
  for (int i = 0; i < 4; ++i)
#pragma unroll
    for (int j = 0; j < 4; ++j) acc[i][j] = (f32x4){0, 0, 0, 0};

#pragma unroll
  for (int e = 0; e < 2; ++e) {
    gload_lds16(gA[e], &astg[0][lA[e]]);
    gload_lds16(gB[e], &bstg[0][lB[e]]);
  }
  for (int it = 0; it < 32; ++it) {
    __syncthreads();
    if (it < 31) {
#pragma unroll
      for (int e = 0; e < 2; ++e) {
        gload_lds16(gA[e] + (it + 1) * 32, &astg[(it + 1) & 1][lA[e]]);
        gload_lds16(gB[e] + (size_t)(it + 1) * 512, &bstg[(it + 1) & 1][lB[e]]);
      }
    }
    const bf16* ab = astg[it & 1];
    const bf16* bb = bstg[it & 1];
    bf16x8 af[4], bfr[4];
#pragma unroll
    for (int i = 0; i < 4; ++i) af[i] = *(const bf16x8*)(ab + (wr * 4 + i) * 512 + lane * 8);
#pragma unroll
    for (int j = 0; j < 4; ++j) bfr[j] = *(const bf16x8*)(bb + (wc * 4 + j) * 512 + lane * 8);
#pragma unroll
    for (int i = 0; i < 4; ++i)
#pragma unroll
      for (int j = 0; j < 4; ++j)
        acc[i][j] = __builtin_amdgcn_mfma_f32_16x16x32_bf16(af[i], bfr[j], acc[i][j], 0, 0, 0);
  }
  // C/D layout: col=lane&15, row=(lane>>4)*4+r [m89-verified]
#pragma unroll
  for (int j = 0; j < 4; ++j) {
    const int col = ct * 128 + wc * 64 + j * 16 + (lane & 15);
    float bv = 0.f;
    if (MODE == 0) {
      const int rem = col & 63;
      bv = bias[(rem & 3) * HH + (col >> 6) * 16 + (rem >> 2)];
    }
#pragma unroll
    for (int i = 0; i < 4; ++i) {
      const int row0 = rt * 128 + wr * 64 + i * 16 + (lane >> 4) * 4;
#pragma unroll
      for (int r = 0; r < 4; ++r) {
        const int row = row0 + r;
        size_t idx;
        if (MODE == 0) idx = (size_t)row * NOUT + col;  // rows are t*NB+n
        else           idx = (size_t)(row >> 4) * (NOUT * 16) + (size_t)col * 16 + (row & 15);
        C[idx] = (bf16)(acc[i][j][r] + bv);
      }
    }
  }
}

// ---- per-step kernel (R20-proven: LDS staging + early-issue + 2-deep B) -----
#define STEP_SMEM 65536
__global__ __launch_bounds__(512, 4) void step_kernel(
    const bf16* __restrict__ Aop_cur, bf16* __restrict__ Aop_nxt,
    const bf16* __restrict__ Wh_t, const bf16* __restrict__ xWx2,
    const bf16* __restrict__ G2, const float* __restrict__ s_cur,
    float* __restrict__ s_nxt, float* __restrict__ s_zro,
    const bf16* __restrict__ A_bf, float* __restrict__ c_ws,
    float* __restrict__ out, const int t) {
  __shared__ __align__(16) char smem[STEP_SMEM];
  __shared__ float w_sh[512];
  bf16* astg = (bf16*)smem;   // [kg][mt*8+ks][512] = 64 KB (one-shot)
  float* red = (float*)smem;  // union after GEMM

  const int b = blockIdx.x;
  const int xcd = b & 7;
  const int ht = xcd * 8 + ((b >> 3) & 7);  // [0,64)
  const int rt = b >> 6;                    // [0,8)
  const int tid = threadIdx.x, lane = tid & 63, wid = tid >> 6;
  const int kg = wid >> 1, ow = wid & 1;
  const int nloc = tid >> 4, hl = tid & 15;
  const int n = rt * 32 + nloc, h = ht * 16 + hl;

  // score read FIRST (its waitcnt then only covers this one load)
  float ss = s_cur[n * 16 + hl];

  // one-shot A staging: wave wid issues tiles tau = wid*8+e
#pragma unroll
  for (int e = 0; e < 8; ++e) {
    const int tau = wid * 8 + e;
    const int tkg = tau >> 4, tmt = (tau >> 3) & 1, tks = tau & 7;
    const bf16* src = Aop_cur +
        (size_t)(rt * 32 + tmt * 16 + (lane & 15)) * 1024 +
        tkg * 256 + tks * 32 + (lane >> 4) * 8;
    gload_lds16(src, astg + tkg * 8192 + (tmt * 8 + tks) * 512);
  }

  // early-issue (T14): G2 block + xWx2 + c_ws + first 2 B fragments
  bf16x8 gq[8];
  {
    const bf16* Gp = G2 + (size_t)n * (NOUT * 16) + (size_t)(ht * 64 + hl * 4) * 16;
#pragma unroll
    for (int e = 0; e < 8; ++e) gq[e] = *(const bf16x8*)(Gp + e * 8);
  }
  const bf16x4 xv = *(const bf16x4*)(xWx2 + (size_t)t * (NB * NOUT) +
                                     (size_t)n * NOUT + ht * 64 + hl * 4);
  const float cold = c_ws[(n << 10) + h];
  const bf16* gB0 = Wh_t + ((size_t)(ht * 4 + ow * 2 + 0) * 32 + kg * 8) * 512 + lane * 8;
  const bf16* gB1 = Wh_t + ((size_t)(ht * 4 + ow * 2 + 1) * 32 + kg * 8) * 512 + lane * 8;
  bf16x8 bc0 = *(const bf16x8*)gB0;
  bf16x8 bc1 = *(const bf16x8*)gB1;
  bf16x8 bd0 = *(const bf16x8*)(gB0 + 512);
  bf16x8 bd1 = *(const bf16x8*)(gB1 + 512);
  // zero the t+2 score buffer (32 B per wg)
  if (tid < 8) s_zro[b * 8 + tid] = 0.f;

  // softmax over p within 16-lane groups
  {
    ss *= 0.03125f;  // 1/sqrt(1024)
    float m = ss;
    SWZ_MAX(m, 0x041F); SWZ_MAX(m, 0x081F); SWZ_MAX(m, 0x101F); SWZ_MAX(m, 0x201F);
    const float e = expf(ss - m);
    float su = e;
    SWZ_ADD(su, 0x041F); SWZ_ADD(su, 0x081F); SWZ_ADD(su, 0x101F); SWZ_ADD(su, 0x201F);
    w_sh[tid] = e / su;
  }
  __syncthreads();  // single drain: staging + all early-issue loads landed

  // ---- GEMM: wave (kg,ow) does K=256, 8 ks x 4 MFMA, B rolling 2-ahead ----
  f32x4 a00 = {0, 0, 0, 0}, a01 = {0, 0, 0, 0}, a10 = {0, 0, 0, 0}, a11 = {0, 0, 0, 0};
  {
    const bf16* ab = astg + kg * 8192;
    __builtin_amdgcn_s_setprio(1);
#pragma unroll
    for (int ks = 0; ks < 8; ++ks) {
      bf16x8 bn0, bn1;
      if (ks < 6) {
        bn0 = *(const bf16x8*)(gB0 + (ks + 2) * 512);
        bn1 = *(const bf16x8*)(gB1 + (ks + 2) * 512);
      }
      const bf16x8 f0 = *(const bf16x8*)(ab + ks * 512 + lane * 8);
      const bf16x8 f1 = *(const bf16x8*)(ab + (8 + ks) * 512 + lane * 8);
      a00 = __builtin_amdgcn_mfma_f32_16x16x32_bf16(f0, bc0, a00, 0, 0, 0);
      a01 = __builtin_amdgcn_mfma_f32_16x16x32_bf16(f0, bc1, a01, 0, 0, 0);
      a10 = __builtin_amdgcn_mfma_f32_16x16x32_bf16(f1, bc0, a10, 0, 0, 0);
      a11 = __builtin_amdgcn_mfma_f32_16x16x32_bf16(f1, bc1, a11, 0, 0, 0);
      bc0 = bd0; bc1 = bd1;
      if (ks < 6) { bd0 = bn0; bd1 = bn1; }
    }
    __builtin_amdgcn_s_setprio(0);
  }
  __syncthreads();  // astg dead -> red live

  // fragment -> red[(kg*64 + c)*36 + nn]; c = ow*32 + j*16 + (lane&15)
  {
    const int cb = kg * 64 + ow * 32 + (lane & 15);
    const int nb = (lane >> 4) * 4;
    *(f32x4*)&red[(cb)*36 + nb] = a00;
    *(f32x4*)&red[(cb + 16) * 36 + nb] = a01;
    *(f32x4*)&red[(cb)*36 + nb + 16] = a10;
    *(f32x4*)&red[(cb + 16) * 36 + nb + 16] = a11;
  }
  __syncthreads();

  // ---- cell ----
  f32x4 gv = {0, 0, 0, 0};
#pragma unroll
  for (int k2 = 0; k2 < 4; ++k2)
#pragma unroll
    for (int g = 0; g < 4; ++g) gv[g] += red[(k2 * 64 + hl * 4 + g) * 36 + nloc];
  // attn term: gv[g] += sum_p w[p] * G2[n][hl*4+g][p]
#pragma unroll
  for (int g = 0; g < 4; ++g) {
    float a0 = 0.f;
#pragma unroll
    for (int p = 0; p < 8; ++p) a0 = fmaf(w_sh[nloc * 16 + p], (float)gq[g * 2][p], a0);
#pragma unroll
    for (int p = 0; p < 8; ++p) a0 = fmaf(w_sh[nloc * 16 + 8 + p], (float)gq[g * 2 + 1][p], a0);
    gv[g] += a0;
  }
  const float ai = gv[0] + (float)xv[0];
  const float af = gv[1] + (float)xv[1];
  const float ao = gv[2] + (float)xv[2];
  const float ag = gv[3] + (float)xv[3];
  const float si = 1.f / (1.f + expf(-ai));
  const float sf = 1.f / (1.f + expf(-af));
  const float so = 1.f / (1.f + expf(-ao));
  const float cn = sf * cold + si * tanhf(ag);
  const float hn = so * tanhf(cn);
  c_ws[(n << 10) + h] = cn;
  __builtin_nontemporal_store(hn, &out[((size_t)n * TS + t) * HH + h]);
  Aop_nxt[(n << 10) + h] = (bf16)hn;

  if (t < TS - 1) {  // next-step score partials: LDS transpose + atomicAdd
    __syncthreads();  // red gate-reads done -> reuse as transpose buffer
    const bf16* arow = A_bf + ((size_t)n * HH + h) * 16;
    const bf16x8 av0 = *(const bf16x8*)arow;
    const bf16x8 av1 = *(const bf16x8*)(arow + 8);
#pragma unroll
    for (int r = 0; r < 8; ++r) {
      red[(nloc * 16 + r) * 17 + hl] = hn * (float)av0[r];
      red[(nloc * 16 + 8 + r) * 17 + hl] = hn * (float)av1[r];
    }
    __syncthreads();
    const float* r2 = &red[(nloc * 16 + hl) * 17];  // p = hl, sum over 16 h
    float s = 0.f;
#pragma unroll
    for (int q = 0; q < 16; ++q) s += r2[q];
    atomicAdd(&s_nxt[n * 16 + hl], s);  // device-scope [m20]
  }
}

// ---------------------------------------------------------------------------
// ws layout (bytes), ~245 MB of 256 MiB:
//   [0, 8388608)             Wh_t   bf16 tiles (1024x4096, cx cols)
//   [8388608, 16777216)      Wat_t  bf16 tiles (1024x4096, cx cols)
//   [16777216, 25165824)     At     bf16 (4096x1024)
//   [25165824, 33554432)     A_bf   bf16 (256x1024x16)
//   [33554432, 167772160)    xWx2   bf16 [t][n][cx] (+bias)
//   [167772160, 201326592)   G2     bf16 [n][cx][p]
//   [201326592, 234881024)   x_bf   bf16 [t][n][d]   [transient]
//   [234881024, 243269632)   Wxt    bf16 tiles        [transient]
//   [243269632, 243793920)   Aop0   bf16 (256x1024)
//   [243793920, 244318208)   Aop1   bf16 (256x1024)
//   [244318208, 244334592)   s0     f32 (256x16)
//   [244334592, 244350976)   s1     f32 (256x16)  [memset 0 each call]
//   [244350976, 244367360)   s2     f32 (256x16)  [zeroed by step t=0]
//   [244367360, 245415936)   c_ws   f32 (256x1024)
// ---------------------------------------------------------------------------
extern "C" void kernel_launch(void* const* d_in, const int* in_sizes, int n_in,
                              void* d_out, int out_size, void* d_ws, size_t ws_size,
                              hipStream_t stream) {
  const float* x     = (const float*)d_in[0];
  const float* A     = (const float*)d_in[1];
  const float* Wx    = (const float*)d_in[2];
  const float* Wh    = (const float*)d_in[3];
  const float* Wattn = (const float*)d_in[4];
  const float* bias  = (const float*)d_in[5];
  float* out = (float*)d_out;
  char* ws = (char*)d_ws;
  bf16* Wh_t   = (bf16*)(ws + 0);
  bf16* Wat_t  = (bf16*)(ws + 8388608);
  bf16* At     = (bf16*)(ws + 16777216);
  bf16* A_bf   = (bf16*)(ws + 25165824);
  bf16* xWx2   = (bf16*)(ws + 33554432);
  bf16* G2     = (bf16*)(ws + 167772160);
  bf16* x_bf   = (bf16*)(ws + 201326592);
  bf16* Wxt    = (bf16*)(ws + 234881024);
  bf16* Aop0   = (bf16*)(ws + 243269632);
  bf16* Aop1   = (bf16*)(ws + 243793920);
  float* s0    = (float*)(ws + 244318208);
  float* s1    = (float*)(ws + 244334592);
  float* s2    = (float*)(ws + 244350976);
  float* c_ws  = (float*)(ws + 244367360);

  hipMemsetAsync(s1, 0, 16384, stream);
  convert_x<<<8192, 256, 0, stream>>>(x, x_bf);
  prep_A<<<256, 1024, 0, stream>>>(A, A_bf, At, c_ws, Aop0, s0);
  convert_wt3<<<384, 256, 0, stream>>>(Wx, Wh, Wattn, Wxt, Wh_t, Wat_t);
  gemm128<0><<<4096, 256, 0, stream>>>(x_bf, Wxt, xWx2, bias);  // x@Wx + bias
  gemm128<1><<<1024, 256, 0, stream>>>(At, Wat_t, G2, nullptr); // G2 = A^T@Wattn
  for (int t = 0; t < TS; ++t) {
    float* scur = (t % 3 == 0) ? s0 : (t % 3 == 1) ? s1 : s2;
    float* snxt = (t % 3 == 0) ? s1 : (t % 3 == 1) ? s2 : s0;
    float* szro = (t % 3 == 0) ? s2 : (t % 3 == 1) ? s0 : s1;
    step_kernel<<<512, 512, 0, stream>>>((t & 1) ? Aop1 : Aop0,
                                         (t & 1) ? Aop0 : Aop1, Wh_t, xWx2,
                                         G2, scur, snxt, szro, A_bf, c_ws,
                                         out, t);
  }
}